// Round 13
// baseline (237.441 us; speedup 1.0000x reference)
//
#include <hip/hip_runtime.h>
#include <hip/hip_bf16.h>
#include <hip/hip_fp8.h>
#include <stdint.h>
#include <math.h>

#define N_ROWS 8192
#define DIM    512
#define BM     128
#define BK     64
#define NB     (N_ROWS / BM)          // 64 block-rows
#define NTRI   (NB * (NB + 1) / 2)    // 2080 triangle tiles
#define NKT    (DIM / BK)             // 8 K-steps

typedef float f32x4 __attribute__((ext_vector_type(4)));
typedef long  lng2  __attribute__((ext_vector_type(2)));

// f_q row layout (per 64-k block kt, slot u in 0..3, 16B/slot):
//   slot bytes 0..7  = k in [kt*64 + u*8,      +8)
//   slot bytes 8..15 = k in [kt*64 + 32 + u*8, +8)
// ONE b128 read gives a lane both kk-halves for the 16x16x32 fp8 MFMA pair.
// Bonus: 8 consecutive k's (j = k&7) are 8 CONTIGUOUS bytes -> k_prep stores 8B/lane.

// ---- fused prep (wave-per-row): normalize f -> fp8, posdot, zero S/K/done ----
__global__ __launch_bounds__(256) void k_prep(const float* __restrict__ feats,
                                              const float* __restrict__ centers,
                                              const int* __restrict__ labels,
                                              unsigned char* __restrict__ f_q,
                                              float* __restrict__ posdot,
                                              float* __restrict__ Ssum,
                                              int* __restrict__ Kcnt,
                                              unsigned int* __restrict__ done) {
    const int tid  = threadIdx.x;
    const int lane = tid & 63;
    const int w    = tid >> 6;
    const int row  = blockIdx.x * 4 + w;
    if (blockIdx.x == 0 && tid == 0) *done = 0u;

    const float* src = feats + (size_t)row * DIM + lane * 8;
    const f32x4 v0 = *(const f32x4*)(src);
    const f32x4 v1 = *(const f32x4*)(src + 4);
    float ss = v0.x*v0.x + v0.y*v0.y + v0.z*v0.z + v0.w*v0.w
             + v1.x*v1.x + v1.y*v1.y + v1.z*v1.z + v1.w*v1.w;
#pragma unroll
    for (int m = 1; m < 64; m <<= 1) ss += __shfl_xor(ss, m, 64);
    const float scale = 1.0f / fmaxf(sqrtf(ss), 1e-12f);

    float vals[8] = { v0.x*scale, v0.y*scale, v0.z*scale, v0.w*scale,
                      v1.x*scale, v1.y*scale, v1.z*scale, v1.w*scale };
    unsigned long long packed = 0ull;
#pragma unroll
    for (int j = 0; j < 8; ++j) {
        __hip_fp8_e4m3 q(vals[j]);
        packed |= (unsigned long long)(*reinterpret_cast<const unsigned char*>(&q)) << (8 * j);
    }
    // k = lane*8 .. lane*8+7 share kt,u,h -> one contiguous 8B store
    const int k  = lane * 8;
    const int kt = k >> 6, k6 = k & 63;
    const int h  = (k6 >> 5) & 1, u = (k6 >> 3) & 3;
    *reinterpret_cast<unsigned long long*>(f_q + (size_t)row * DIM + kt * 64 + u * 16 + h * 8) = packed;

    const int lab = labels[row];
    const float* c = centers + (size_t)lab * DIM + lane * 8;
    const f32x4 c0 = *(const f32x4*)(c);
    const f32x4 c1 = *(const f32x4*)(c + 4);
    float cc = c0.x*c0.x + c0.y*c0.y + c0.z*c0.z + c0.w*c0.w
             + c1.x*c1.x + c1.y*c1.y + c1.z*c1.z + c1.w*c1.w;
    float d  = vals[0]*c0.x + vals[1]*c0.y + vals[2]*c0.z + vals[3]*c0.w
             + vals[4]*c1.x + vals[5]*c1.y + vals[6]*c1.z + vals[7]*c1.w;
#pragma unroll
    for (int m = 1; m < 64; m <<= 1) {
        cc += __shfl_xor(cc, m, 64);
        d  += __shfl_xor(d, m, 64);
    }
    if (lane == 0) {
        posdot[row] = d / fmaxf(sqrtf(cc), 1e-12f);
        Ssum[row] = 0.0f;
        Kcnt[row] = 0;
    }
}

// ---------------- fused triangular A*A^T fp8 GEMM + masked row/col reduction ---
// R9-proven core: 2-buffer 2-phase dbuf, conflict-free b128 pair-interleaved
// fragment reads, 34.9 KB LDS -> 4 blocks/CU, VGPR ~84. Appended: last-block
// final reduction (device atomic counter) replaces the separate k_final launch.
__global__ __launch_bounds__(256) void k_pair(const unsigned char* __restrict__ f_q,
                                              const int* __restrict__ labels,
                                              const float* __restrict__ pd,
                                              float* __restrict__ Ssum,
                                              int* __restrict__ Kcnt,
                                              unsigned int* __restrict__ done,
                                              float* __restrict__ out) {
    __shared__ __align__(16) unsigned char sA[2][BM * BK];
    __shared__ __align__(16) unsigned char sB[2][BM * BK];
    __shared__ int   s_lr[BM];
    __shared__ int   s_lc[BM];
    __shared__ float s_pd[BM];
    __shared__ float s_pc[BM];

    const int tid  = threadIdx.x;
    const int lane = tid & 63;
    const int wid  = tid >> 6;
    const int wr   = wid >> 1, wc = wid & 1;

    // triangle index -> (bi, bj), bi <= bj
    const int t = blockIdx.x;
    int bi = (int)floor((2.0 * NB + 1.0 - sqrt((2.0 * NB + 1.0) * (2.0 * NB + 1.0) - 8.0 * (double)t)) * 0.5);
    while (bi * NB - bi * (bi - 1) / 2 > t) --bi;
    while ((bi + 1) * NB - (bi + 1) * bi / 2 <= t) ++bi;
    const int bj = bi + (t - (bi * NB - bi * (bi - 1) / 2));
    const int rowBase = bi * BM;
    const int colBase = bj * BM;
    const bool offdiag = (bi != bj);

    if (tid < BM) {
        s_lr[tid] = labels[rowBase + tid];
        s_pd[tid] = pd[rowBase + tid];
    } else {
        s_lc[tid - BM] = labels[colBase + tid - BM];
        s_pc[tid - BM] = pd[colBase + tid - BM];
    }

    f32x4 acc[4][4] = {};

    const int srow = lane >> 2;
    const int slu  = (lane & 3) ^ ((lane >> 3) & 3);

#define STAGE(KT, P)                                                                       \
    do {                                                                                   \
        const int k0_ = (KT) * BK;                                                         \
        _Pragma("unroll")                                                                  \
        for (int i_ = 0; i_ < 2; ++i_) {                                                   \
            const int ch_ = wid * 2 + i_;                                                  \
            const int r_  = ch_ * 16 + srow;                                               \
            const unsigned char* gA_ = f_q + ((size_t)(rowBase + r_) * DIM + k0_ + slu * 16); \
            const unsigned char* gB_ = f_q + ((size_t)(colBase + r_) * DIM + k0_ + slu * 16); \
            __builtin_amdgcn_global_load_lds(                                              \
                (const __attribute__((address_space(1))) void*)gA_,                        \
                (__attribute__((address_space(3))) void*)(&sA[P][ch_ * 1024]), 16, 0, 0);  \
            __builtin_amdgcn_global_load_lds(                                              \
                (const __attribute__((address_space(1))) void*)gB_,                        \
                (__attribute__((address_space(3))) void*)(&sB[P][ch_ * 1024]), 16, 0, 0);  \
        }                                                                                  \
    } while (0)

    const int pu = (lane >> 4) ^ ((lane >> 1) & 3);

#define COMPUTE(P)                                                                         \
    do {                                                                                   \
        lng2 aF[4], bF[4];                                                                 \
        _Pragma("unroll")                                                                  \
        for (int m = 0; m < 4; ++m) {                                                      \
            const int r = wr * 64 + m * 16 + (lane & 15);                                  \
            aF[m] = *(const lng2*)(&sA[P][r * 64 + pu * 16]);                              \
        }                                                                                  \
        _Pragma("unroll")                                                                  \
        for (int n = 0; n < 4; ++n) {                                                      \
            const int r = wc * 64 + n * 16 + (lane & 15);                                  \
            bF[n] = *(const lng2*)(&sB[P][r * 64 + pu * 16]);                              \
        }                                                                                  \
        _Pragma("unroll")                                                                  \
        for (int m = 0; m < 4; ++m)                                                        \
            _Pragma("unroll")                                                              \
            for (int n = 0; n < 4; ++n) {                                                  \
                acc[m][n] = __builtin_amdgcn_mfma_f32_16x16x32_fp8_fp8(aF[m].x, bF[n].x, acc[m][n], 0, 0, 0); \
                acc[m][n] = __builtin_amdgcn_mfma_f32_16x16x32_fp8_fp8(aF[m].y, bF[n].y, acc[m][n], 0, 0, 0); \
            }                                                                              \
    } while (0)

    STAGE(0, 0);
    __syncthreads();   // drains stage(0) + publishes s_lr/s_pd/s_lc/s_pc

    for (int kt = 0; kt < NKT - 1; ++kt) {
        const int cur = kt & 1;
        STAGE(kt + 1, cur ^ 1);
        COMPUTE(cur);
        __syncthreads();
    }
    COMPUTE((NKT - 1) & 1);

#undef STAGE
#undef COMPUTE

    // ---- masked row + column reduction epilogue ----
    float colS[4] = {0.f, 0.f, 0.f, 0.f};
    int   colK[4] = {0, 0, 0, 0};
    int   lcv[4]; float pcv[4];
#pragma unroll
    for (int n = 0; n < 4; ++n) {
        const int jl = wc * 64 + n * 16 + (lane & 15);
        lcv[n] = s_lc[jl];
        pcv[n] = s_pc[jl];
    }

#pragma unroll
    for (int m = 0; m < 4; ++m) {
        float rowS[4] = {0.f, 0.f, 0.f, 0.f};
        int   rowK[4] = {0, 0, 0, 0};
        const int rbase = wr * 64 + m * 16 + ((lane >> 4) << 2);
        int myLr[4]; float myPd[4];
#pragma unroll
        for (int g = 0; g < 4; ++g) { myLr[g] = s_lr[rbase + g]; myPd[g] = s_pd[rbase + g]; }
#pragma unroll
        for (int n = 0; n < 4; ++n) {
#pragma unroll
            for (int g = 0; g < 4; ++g) {
                const float s = acc[m][n][g];
                const bool diff = (myLr[g] != lcv[n]);
                if (diff && s > myPd[g]) { rowS[g] += (s - myPd[g]); rowK[g] += 1; }
                if (offdiag && diff && s > pcv[n]) { colS[n] += (s - pcv[n]); colK[n] += 1; }
            }
        }
#pragma unroll
        for (int g = 0; g < 4; ++g) {
#pragma unroll
            for (int d = 1; d < 16; d <<= 1) {
                rowS[g] += __shfl_xor(rowS[g], d, 64);
                rowK[g] += __shfl_xor(rowK[g], d, 64);
            }
        }
        if ((lane & 15) == 0) {
#pragma unroll
            for (int g = 0; g < 4; ++g) {
                const int r = rowBase + rbase + g;
                atomicAdd(&Ssum[r], rowS[g]);
                atomicAdd(&Kcnt[r], rowK[g]);
            }
        }
    }

    if (offdiag) {
#pragma unroll
        for (int n = 0; n < 4; ++n) {
#pragma unroll
            for (int d = 16; d < 64; d <<= 1) {
                colS[n] += __shfl_xor(colS[n], d, 64);
                colK[n] += __shfl_xor(colK[n], d, 64);
            }
        }
        if (lane < 16) {
#pragma unroll
            for (int n = 0; n < 4; ++n) {
                const int c = colBase + wc * 64 + n * 16 + lane;
                atomicAdd(&Ssum[c], colS[n]);
                atomicAdd(&Kcnt[c], colK[n]);
            }
        }
    }

    // ---- last-block-done final reduction (replaces k_final launch) ----
    __threadfence();
    __shared__ unsigned int s_last;
    __shared__ double s_dsum[4];
    __shared__ int    s_dcnt[4];
    if (tid == 0) s_last = (atomicAdd(done, 1u) == (unsigned)(NTRI - 1)) ? 1u : 0u;
    __syncthreads();
    if (s_last) {
        double sum = 0.0; int cnt = 0;
        for (int i = tid; i < N_ROWS; i += 256) {
            const int k = __hip_atomic_load(&Kcnt[i], __ATOMIC_RELAXED, __HIP_MEMORY_SCOPE_AGENT);
            if (k > 0) {
                const float s = __hip_atomic_load(&Ssum[i], __ATOMIC_RELAXED, __HIP_MEMORY_SCOPE_AGENT);
                sum += (double)s / (double)k;
                cnt += 1;
            }
        }
#pragma unroll
        for (int d = 1; d < 64; d <<= 1) {
            sum += __shfl_xor(sum, d, 64);
            cnt += __shfl_xor(cnt, d, 64);
        }
        if (lane == 0) { s_dsum[wid] = sum; s_dcnt[wid] = cnt; }
        __syncthreads();
        if (tid == 0) {
            const double ts = s_dsum[0] + s_dsum[1] + s_dsum[2] + s_dsum[3];
            const int    tc = s_dcnt[0] + s_dcnt[1] + s_dcnt[2] + s_dcnt[3];
            out[0] = (float)(tc > 0 ? ts / (double)tc : ts);
        }
    }
}

extern "C" void kernel_launch(void* const* d_in, const int* in_sizes, int n_in,
                              void* d_out, int out_size, void* d_ws, size_t ws_size,
                              hipStream_t stream) {
    const float* features = (const float*)d_in[0];
    const float* centers  = (const float*)d_in[1];
    const int*   labels   = (const int*)d_in[2];
    float* out = (float*)d_out;

    char* ws = (char*)d_ws;
    unsigned char* f_q    = (unsigned char*)(ws);                 // 4,194,304 B
    float*         posdot = (float*)(ws + 0x400000);              // 32,768 B
    float*         Ssum   = (float*)(ws + 0x400000 + 0x8000);
    int*           Kcnt   = (int*)  (ws + 0x400000 + 0x10000);
    unsigned int*  done   = (unsigned int*)(ws + 0x400000 + 0x18000);

    k_prep<<<N_ROWS / 4, 256, 0, stream>>>(features, centers, labels, f_q, posdot, Ssum, Kcnt, done);
    k_pair<<<NTRI, 256, 0, stream>>>(f_q, labels, posdot, Ssum, Kcnt, done, out);
}